// Round 4
// baseline (107.416 us; speedup 1.0000x reference)
//
#include <hip/hip_runtime.h>

#define THREADS 256
#define QPT 8              // queries per thread
#define SLICES 32
#define NPTS 8192
#define BATCH 4
#define SLICE (NPTS / SLICES)   // 256 targets per block

// partials ws layout: [SLICES][2*BATCH][NPTS] float = 32*8*8192*4 = 8 MB
// fallback ws layout: [2*BATCH][NPTS] uint min arrays = 256 KB

__global__ void chamfer_init(unsigned int* mins) {
    int i = blockIdx.x * blockDim.x + threadIdx.x;
    mins[i] = 0x7F800000u;  // +inf
}

__global__ __launch_bounds__(THREADS) void chamfer_main(
    const float* __restrict__ p1, const float* __restrict__ p2,
    float* __restrict__ ws, int use_partials)
{
    const int tid  = threadIdx.x;
    const int dirb = blockIdx.z;         // 0..7 : dir*4 + batch
    const int dir  = dirb >> 2;
    const int b    = dirb & 3;
    const int qbase = blockIdx.x * (THREADS * QPT);
    const int tbase = blockIdx.y * SLICE;

    const float* __restrict__ qsrc = (dir == 0) ? p1 : p2;
    const float* __restrict__ tsrc = (dir == 0) ? p2 : p1;

    // ---- stage transformed targets into LDS: (-2x, -2y, -2z, |t|^2) ----
    __shared__ float4 tgt[SLICE];
    {
        const float* tp = tsrc + ((size_t)b * NPTS + tbase) * 3;
        for (int k = tid; k < SLICE; k += THREADS) {
            float x = tp[k * 3 + 0];
            float y = tp[k * 3 + 1];
            float z = tp[k * 3 + 2];
            tgt[k] = make_float4(-2.0f * x, -2.0f * y, -2.0f * z,
                                 fmaf(x, x, fmaf(y, y, z * z)));
        }
    }

    // ---- load this thread's queries ----
    float ax[QPT], ay[QPT], az[QPT], a2[QPT], best[QPT];
#pragma unroll
    for (int j = 0; j < QPT; ++j) {
        const int q = qbase + j * THREADS + tid;
        const float* qp = qsrc + ((size_t)b * NPTS + q) * 3;
        ax[j] = qp[0]; ay[j] = qp[1]; az[j] = qp[2];
        a2[j] = fmaf(ax[j], ax[j], fmaf(ay[j], ay[j], az[j] * az[j]));
        best[j] = 3.0e38f;
    }

    __syncthreads();

    // ---- main loop: 2 targets/iter, scalar FMA chains, min3 fold ----
#pragma unroll 2
    for (int m = 0; m < SLICE; m += 2) {
        float4 ta = tgt[m];
        float4 tb = tgt[m + 1];
#pragma unroll
        for (int j = 0; j < QPT; ++j) {
            float da = fmaf(ax[j], ta.x, fmaf(ay[j], ta.y, fmaf(az[j], ta.z, ta.w)));
            float db = fmaf(ax[j], tb.x, fmaf(ay[j], tb.y, fmaf(az[j], tb.z, tb.w)));
            best[j] = fminf(fminf(best[j], da), db);   // -> v_min3_f32
        }
    }

    // ---- epilogue: + |q|^2, clamp; store partial min or atomicMin ----
    if (use_partials) {
        float* pbase = ws + (((size_t)blockIdx.y * 8 + dirb) * NPTS);
#pragma unroll
        for (int j = 0; j < QPT; ++j) {
            float v = fmaxf(best[j] + a2[j], 0.0f);
            pbase[qbase + j * THREADS + tid] = v;   // plain coalesced store
        }
    } else {
        unsigned int* mbase = (unsigned int*)ws + ((size_t)dirb * NPTS);
#pragma unroll
        for (int j = 0; j < QPT; ++j) {
            float v = fmaxf(best[j] + a2[j], 0.0f);
            atomicMin(&mbase[qbase + j * THREADS + tid], __float_as_uint(v));
        }
    }
}

// partials reduce: 65536 threads, each min-folds its (dirb,q) over 32 slices
__global__ __launch_bounds__(THREADS) void chamfer_reduce_partials(
    const float* __restrict__ partials, float* __restrict__ out)
{
    const int i = blockIdx.x * THREADS + threadIdx.x;   // [0, 65536)
    const int dirb = i >> 13;
    const int q = i & (NPTS - 1);
    float v = 3.4e38f;
#pragma unroll 8
    for (int s = 0; s < SLICES; ++s)
        v = fminf(v, partials[((size_t)s * 8 + dirb) * NPTS + q]);

    float sv = v;
#pragma unroll
    for (int off = 32; off >= 1; off >>= 1)
        sv += __shfl_down(sv, off, 64);
    __shared__ float partial[THREADS / 64];
    if ((threadIdx.x & 63) == 0) partial[threadIdx.x >> 6] = sv;
    __syncthreads();
    if (threadIdx.x == 0) {
        float tot = 0.0f;
#pragma unroll
        for (int w = 0; w < THREADS / 64; ++w) tot += partial[w];
        atomicAdd(out, tot * (1.0f / (BATCH * NPTS)));
    }
}

// fallback reduce: sum the 65536 uint-min array
__global__ __launch_bounds__(THREADS) void chamfer_reduce_atomic(
    const uint4* __restrict__ mins, float* __restrict__ out)
{
    const int i = blockIdx.x * THREADS + threadIdx.x;
    uint4 u = mins[i];
    float s = __uint_as_float(u.x) + __uint_as_float(u.y)
            + __uint_as_float(u.z) + __uint_as_float(u.w);
#pragma unroll
    for (int off = 32; off >= 1; off >>= 1)
        s += __shfl_down(s, off, 64);
    __shared__ float partial[THREADS / 64];
    if ((threadIdx.x & 63) == 0) partial[threadIdx.x >> 6] = s;
    __syncthreads();
    if (threadIdx.x == 0) {
        float tot = 0.0f;
#pragma unroll
        for (int w = 0; w < THREADS / 64; ++w) tot += partial[w];
        atomicAdd(out, tot * (1.0f / (BATCH * NPTS)));
    }
}

extern "C" void kernel_launch(void* const* d_in, const int* in_sizes, int n_in,
                              void* d_out, int out_size, void* d_ws, size_t ws_size,
                              hipStream_t stream) {
    const float* p1 = (const float*)d_in[0];
    const float* p2 = (const float*)d_in[1];
    float* out = (float*)d_out;

    const size_t need_partials = (size_t)SLICES * 8 * NPTS * 4;   // 8 MB
    const int use_partials = (ws_size >= need_partials) ? 1 : 0;

    hipMemsetAsync(d_out, 0, sizeof(float), stream);

    if (!use_partials) {
        chamfer_init<<<(2 * BATCH * NPTS) / THREADS, THREADS, 0, stream>>>(
            (unsigned int*)d_ws);
    }

    // main: x = query blocks (8192/(256*8)=4), y = slices (32), z = dir*4+batch
    dim3 grid(NPTS / (THREADS * QPT), SLICES, 2 * BATCH);
    chamfer_main<<<grid, THREADS, 0, stream>>>(p1, p2, (float*)d_ws, use_partials);

    if (use_partials) {
        chamfer_reduce_partials<<<(2 * BATCH * NPTS) / THREADS, THREADS, 0, stream>>>(
            (const float*)d_ws, out);
    } else {
        chamfer_reduce_atomic<<<(2 * BATCH * NPTS) / (4 * THREADS), THREADS, 0, stream>>>(
            (const uint4*)d_ws, out);
    }
}